// Round 1
// baseline (197.609 us; speedup 1.0000x reference)
//
#include <hip/hip_runtime.h>

typedef __attribute__((ext_vector_type(8))) unsigned short ushort8;
typedef __attribute__((ext_vector_type(8))) short short8;
typedef __attribute__((ext_vector_type(4))) float f32x4;

#define M_DIM 8192
#define N_DIM 2048
#define K_DIM 2048
#define BM 256
#define BN 256
#define BK 64
#define NT (K_DIM / BK)   // 32 k-tiles

// ---- fp32 -> bf16 (RNE) ----
__device__ __forceinline__ unsigned short f32_to_bf16(float f) {
  unsigned int u = __float_as_uint(f);
  u += 0x7fffu + ((u >> 16) & 1u);
  return (unsigned short)(u >> 16);
}

__global__ void __launch_bounds__(256) cast_both_x8(
    const float* __restrict__ x, const float* __restrict__ W,
    unsigned short* __restrict__ xb, unsigned short* __restrict__ Wb) {
  const long nx = (long)M_DIM * K_DIM;
  long i = ((long)blockIdx.x * 256 + threadIdx.x) * 8;
  const float* s;
  unsigned short* d;
  if (i < nx) { s = x + i; d = xb + i; }
  else        { s = W + (i - nx); d = Wb + (i - nx); }
  float4 a = *(const float4*)(s);
  float4 b = *(const float4*)(s + 4);
  ushort8 r;
  r[0] = f32_to_bf16(a.x); r[1] = f32_to_bf16(a.y);
  r[2] = f32_to_bf16(a.z); r[3] = f32_to_bf16(a.w);
  r[4] = f32_to_bf16(b.x); r[5] = f32_to_bf16(b.y);
  r[6] = f32_to_bf16(b.z); r[7] = f32_to_bf16(b.w);
  *(ushort8*)(d) = r;
}

__device__ __forceinline__ void gload_lds16(const unsigned short* g, unsigned short* l) {
  __builtin_amdgcn_global_load_lds(
      (const __attribute__((address_space(1))) void*)g,
      (__attribute__((address_space(3))) void*)l,
      16, 0, 0);
}

// 256x256 8-phase GEMM: C = A(MxK)*B(NxK)^T + bias.
// 512 thr = 8 waves (2m x 4n), per-wave 128x64 output, 16x16x32 bf16 MFMA.
// LDS 128 KB: 2 dbuf x (A 32KB | B 32KB), chunk-XOR swizzled (0 bank conflicts,
// staged via global_load_lds with pre-swizzled per-lane SOURCE addresses).
// Per K-tile: 4 phases (C-quadrants), each {ds_read; barrier; lgkmcnt(0);
// setprio(1); 16 MFMA; setprio(0); barrier}. Tile t+2 staged in phase 3 with
// counted vmcnt(8) -- 8 loads stay in flight across barriers (never drain to 0).
__global__ void __launch_bounds__(512, 2) gemm_8ph(
    const unsigned short* __restrict__ A,
    const unsigned short* __restrict__ B,
    const float* __restrict__ bias,
    float* __restrict__ C) {
  __shared__ unsigned short lds[2 * 32768];   // [buf][A 16384 | B 16384] elems

  const int tid  = threadIdx.x;
  const int lane = tid & 63;
  const int wave = tid >> 6;
  const int wm   = wave & 1;     // m-half (2)
  const int wn   = wave >> 1;    // n-quarter (4)

  // XCD mapping: consecutive blocks round-robin XCDs -> n-tile == XCD id.
  // Each XCD keeps its 1 MB B-panel L2-resident; A-panels stream via L3 in
  // lockstep across XCDs.
  const int blk = blockIdx.x;
  const int bn0 = (blk & 7) * BN;
  const int bm0 = (blk >> 3) * BM;

  // ---- staging geometry: thread loads 4 A-chunks + 4 B-chunks (16 B each).
  // LDS dest linear (tid*16B + j*8KB); source chunk pre-swizzled: cg = cb^(r&7).
  const int r0 = tid >> 3;                      // 0..63
  const int cg = (tid & 7) ^ (r0 & 7);
  const unsigned short* Ag = A + (size_t)(bm0 + r0) * K_DIM + cg * 8;
  const unsigned short* Bg = B + (size_t)(bn0 + r0) * K_DIM + cg * 8;
  unsigned short* l0 = lds + tid * 8;

#define STAGE(c, t)                                                            \
  do {                                                                         \
    unsigned short* la = l0 + (c) * 32768;                                     \
    const unsigned short* ga = Ag + (t) * BK;                                  \
    const unsigned short* gb = Bg + (t) * BK;                                  \
    _Pragma("unroll")                                                          \
    for (int j = 0; j < 4; ++j) gload_lds16(ga + j * (64 * K_DIM), la + j * 4096); \
    _Pragma("unroll")                                                          \
    for (int j = 0; j < 4; ++j) gload_lds16(gb + j * (64 * K_DIM), la + 16384 + j * 4096); \
  } while (0)

  // ---- fragment LDS offsets (elements); k-half s=1 is offset ^ 32 ----
  const int frow = lane & 15;
  const int q    = lane >> 4;
  int aoff[8], boff[4];
#pragma unroll
  for (int mi = 0; mi < 8; ++mi) {
    int rr = wm * 128 + mi * 16 + frow;
    aoff[mi] = (rr * 8 + (q ^ (rr & 7))) * 8;
  }
#pragma unroll
  for (int ni = 0; ni < 4; ++ni) {
    int rr = wn * 64 + ni * 16 + frow;
    boff[ni] = (rr * 8 + (q ^ (rr & 7))) * 8;
  }

  const int col16 = frow;
  const int row4  = q * 4;
  float bv[4];
#pragma unroll
  for (int ni = 0; ni < 4; ++ni) bv[ni] = bias[bn0 + wn * 64 + ni * 16 + col16];

  f32x4 acc[8][4] = {};

  // prologue: tiles 0 (buf0) and 1 (buf1) in flight; wait tile 0 only.
  STAGE(0, 0);
  STAGE(1, 1);
  asm volatile("s_waitcnt vmcnt(8)" ::: "memory");
  __builtin_amdgcn_s_barrier();

#define PH_OPEN()                                        \
    __builtin_amdgcn_s_barrier();                        \
    asm volatile("s_waitcnt lgkmcnt(0)" ::: "memory");   \
    __builtin_amdgcn_sched_barrier(0);                   \
    __builtin_amdgcn_s_setprio(1)
#define PH_CLOSE()                                       \
    __builtin_amdgcn_s_setprio(0);                       \
    __builtin_amdgcn_sched_barrier(0);                   \
    __builtin_amdgcn_s_barrier()
#define LDA(o) (*(const short8*)(sa + (o)))
#define LDB(o) (*(const short8*)(sb + (o)))

#pragma unroll 2
  for (int t = 0; t < NT; ++t) {
    const unsigned short* sa = lds + (t & 1) * 32768;
    const unsigned short* sb = sa + 16384;
    short8 a[4][2], b01[2][2], b23[2][2];

    // ---------- phase 0 : (m 0-63) x (n 0-31) : 12 ds_reads ----------
#pragma unroll
    for (int mi = 0; mi < 4; ++mi) { a[mi][0] = LDA(aoff[mi]); a[mi][1] = LDA(aoff[mi] ^ 32); }
#pragma unroll
    for (int ni = 0; ni < 2; ++ni) { b01[ni][0] = LDB(boff[ni]); b01[ni][1] = LDB(boff[ni] ^ 32); }
    PH_OPEN();
#pragma unroll
    for (int mi = 0; mi < 4; ++mi)
#pragma unroll
      for (int ni = 0; ni < 2; ++ni)
#pragma unroll
        for (int s = 0; s < 2; ++s)
          acc[mi][ni] = __builtin_amdgcn_mfma_f32_16x16x32_bf16(
              a[mi][s], b01[ni][s], acc[mi][ni], 0, 0, 0);
    PH_CLOSE();

    // ---------- phase 1 : (m 0-63) x (n 32-63) : 4 ds_reads ----------
#pragma unroll
    for (int ni = 0; ni < 2; ++ni) { b23[ni][0] = LDB(boff[ni + 2]); b23[ni][1] = LDB(boff[ni + 2] ^ 32); }
    PH_OPEN();
#pragma unroll
    for (int mi = 0; mi < 4; ++mi)
#pragma unroll
      for (int ni = 0; ni < 2; ++ni)
#pragma unroll
        for (int s = 0; s < 2; ++s)
          acc[mi][ni + 2] = __builtin_amdgcn_mfma_f32_16x16x32_bf16(
              a[mi][s], b23[ni][s], acc[mi][ni + 2], 0, 0, 0);
    PH_CLOSE();

    // ---------- phase 2 : (m 64-127) x (n 0-31) : 8 ds_reads ----------
#pragma unroll
    for (int mi = 0; mi < 4; ++mi) { a[mi][0] = LDA(aoff[mi + 4]); a[mi][1] = LDA(aoff[mi + 4] ^ 32); }
    PH_OPEN();
#pragma unroll
    for (int mi = 0; mi < 4; ++mi)
#pragma unroll
      for (int ni = 0; ni < 2; ++ni)
#pragma unroll
        for (int s = 0; s < 2; ++s)
          acc[mi + 4][ni] = __builtin_amdgcn_mfma_f32_16x16x32_bf16(
              a[mi][s], b01[ni][s], acc[mi + 4][ni], 0, 0, 0);
    PH_CLOSE();

    // ---- phase 3 : (m 64-127) x (n 32-63) + stage tile t+2, counted vmcnt ----
    // buf (t&1) is free for overwrite: its last ds_reads finished before
    // phase 2's closing barrier. vmcnt(8) leaves the 8 just-issued loads in
    // flight while guaranteeing tile t+1 (issued 4 phases ago) has landed.
    if (t + 2 < NT) {
      STAGE(t & 1, t + 2);
      asm volatile("s_waitcnt vmcnt(8)" ::: "memory");
    } else {
      asm volatile("s_waitcnt vmcnt(0)" ::: "memory");
    }
    __builtin_amdgcn_s_barrier();
    __builtin_amdgcn_s_setprio(1);
#pragma unroll
    for (int mi = 0; mi < 4; ++mi)
#pragma unroll
      for (int ni = 0; ni < 2; ++ni)
#pragma unroll
        for (int s = 0; s < 2; ++s)
          acc[mi + 4][ni + 2] = __builtin_amdgcn_mfma_f32_16x16x32_bf16(
              a[mi][s], b23[ni][s], acc[mi + 4][ni + 2], 0, 0, 0);
    PH_CLOSE();
  }

  // ---------------- epilogue: C = acc + bias ----------------
#pragma unroll
  for (int ni = 0; ni < 4; ++ni) {
    const int gcol = bn0 + wn * 64 + ni * 16 + col16;
#pragma unroll
    for (int mi = 0; mi < 8; ++mi) {
      const int grow = bm0 + wm * 128 + mi * 16 + row4;
#pragma unroll
      for (int r = 0; r < 4; ++r)
        C[(size_t)(grow + r) * N_DIM + gcol] = acc[mi][ni][r] + bv[ni];
    }
  }
}

extern "C" void kernel_launch(void* const* d_in, const int* in_sizes, int n_in,
                              void* d_out, int out_size, void* d_ws, size_t ws_size,
                              hipStream_t stream) {
  const float* x = (const float*)d_in[0];
  const float* W = (const float*)d_in[1];
  const float* b = (const float*)d_in[2];
  float* out = (float*)d_out;

  unsigned short* xb = (unsigned short*)d_ws;
  unsigned short* Wb = xb + (size_t)M_DIM * K_DIM;

  const long ntot = (long)M_DIM * K_DIM + (long)N_DIM * K_DIM;
  cast_both_x8<<<(int)(ntot / (256 * 8)), 256, 0, stream>>>(x, W, xb, Wb);

  gemm_8ph<<<256, 512, 0, stream>>>(xb, Wb, b, out);
}

// Round 2
// 193.355 us; speedup vs baseline: 1.0220x; 1.0220x over previous
//
#include <hip/hip_runtime.h>

typedef __attribute__((ext_vector_type(8))) unsigned short ushort8;
typedef __attribute__((ext_vector_type(8))) short short8;
typedef __attribute__((ext_vector_type(4))) float f32x4;

#define M_DIM 8192
#define N_DIM 2048
#define K_DIM 2048
#define BM 256
#define BN 256
#define BK 64
#define NT (K_DIM / BK)   // 32 k-tiles

// ---- fp32 -> bf16 (RNE) ----
__device__ __forceinline__ unsigned short f32_to_bf16(float f) {
  unsigned int u = __float_as_uint(f);
  u += 0x7fffu + ((u >> 16) & 1u);
  return (unsigned short)(u >> 16);
}

__global__ void __launch_bounds__(256) cast_both_x8(
    const float* __restrict__ x, const float* __restrict__ W,
    unsigned short* __restrict__ xb, unsigned short* __restrict__ Wb) {
  const long nx = (long)M_DIM * K_DIM;
  long i = ((long)blockIdx.x * 256 + threadIdx.x) * 8;
  const float* s;
  unsigned short* d;
  if (i < nx) { s = x + i; d = xb + i; }
  else        { s = W + (i - nx); d = Wb + (i - nx); }
  float4 a = *(const float4*)(s);
  float4 b = *(const float4*)(s + 4);
  ushort8 r;
  r[0] = f32_to_bf16(a.x); r[1] = f32_to_bf16(a.y);
  r[2] = f32_to_bf16(a.z); r[3] = f32_to_bf16(a.w);
  r[4] = f32_to_bf16(b.x); r[5] = f32_to_bf16(b.y);
  r[6] = f32_to_bf16(b.z); r[7] = f32_to_bf16(b.w);
  *(ushort8*)(d) = r;
}

__device__ __forceinline__ void gload_lds16(const unsigned short* g, unsigned short* l) {
  __builtin_amdgcn_global_load_lds(
      (const __attribute__((address_space(1))) void*)g,
      (__attribute__((address_space(3))) void*)l,
      16, 0, 0);
}

// 256x256 8-phase GEMM: C = A(MxK)*B(NxK)^T + bias.
// 512 thr = 8 waves (2m x 4n), per-wave 128x64 output, 16x16x32 bf16 MFMA.
// LDS 128 KB: 2 dbuf x (A 32KB | B 32KB), chunk-XOR swizzled (0 bank conflicts,
// staged via global_load_lds with pre-swizzled per-lane SOURCE addresses).
// XCD map: A-resident. xcd = blk&7 owns m-tiles {4x..4x+3} (A 4MB fits its L2);
// B (8MB) is the only cross-XCD stream and lives in L3. This is the round-2
// fix for FETCH_SIZE=135MB (old map streamed all 32MB of A through each L2).
__global__ void __launch_bounds__(512, 2) gemm_8ph(
    const unsigned short* __restrict__ A,
    const unsigned short* __restrict__ B,
    const float* __restrict__ bias,
    float* __restrict__ C) {
  __shared__ unsigned short lds[2 * 32768];   // [buf][A 16384 | B 16384] elems

  const int tid  = threadIdx.x;
  const int lane = tid & 63;
  const int wave = tid >> 6;
  const int wm   = wave & 1;     // m-half (2)
  const int wn   = wave >> 1;    // n-quarter (4)

  // Bijective A-resident remap: 256 blocks = 32 m-tiles x 8 n-tiles.
  const int blk = blockIdx.x;
  const int xcd = blk & 7;
  const int bi  = blk >> 3;                 // 0..31 within XCD
  const int bm0 = (xcd * 4 + (bi & 3)) * BM;
  const int bn0 = (bi >> 2) * BN;

  // ---- staging geometry: thread loads 4 A-chunks + 4 B-chunks (16 B each).
  // LDS dest linear (tid*16B + j*8KB); source chunk pre-swizzled: cg = cb^(r&7).
  const int r0 = tid >> 3;                      // 0..63
  const int cg = (tid & 7) ^ (r0 & 7);
  const unsigned short* Ag = A + (size_t)(bm0 + r0) * K_DIM + cg * 8;
  const unsigned short* Bg = B + (size_t)(bn0 + r0) * K_DIM + cg * 8;
  unsigned short* l0 = lds + tid * 8;

#define STAGE(c, t)                                                            \
  do {                                                                         \
    unsigned short* la = l0 + (c) * 32768;                                     \
    const unsigned short* ga = Ag + (t) * BK;                                  \
    const unsigned short* gb = Bg + (t) * BK;                                  \
    _Pragma("unroll")                                                          \
    for (int j = 0; j < 4; ++j) gload_lds16(ga + j * (64 * K_DIM), la + j * 4096); \
    _Pragma("unroll")                                                          \
    for (int j = 0; j < 4; ++j) gload_lds16(gb + j * (64 * K_DIM), la + 16384 + j * 4096); \
  } while (0)

  // ---- fragment LDS offsets (elements); k-half s=1 is offset ^ 32 ----
  const int frow = lane & 15;
  const int q    = lane >> 4;
  int aoff[8], boff[4];
#pragma unroll
  for (int mi = 0; mi < 8; ++mi) {
    int rr = wm * 128 + mi * 16 + frow;
    aoff[mi] = (rr * 8 + (q ^ (rr & 7))) * 8;
  }
#pragma unroll
  for (int ni = 0; ni < 4; ++ni) {
    int rr = wn * 64 + ni * 16 + frow;
    boff[ni] = (rr * 8 + (q ^ (rr & 7))) * 8;
  }

  const int col16 = frow;
  const int row4  = q * 4;
  float bv[4];
#pragma unroll
  for (int ni = 0; ni < 4; ++ni) bv[ni] = bias[bn0 + wn * 64 + ni * 16 + col16];

  f32x4 acc[8][4] = {};

  // prologue: tiles 0 (buf0) and 1 (buf1) in flight; wait tile 0 only.
  STAGE(0, 0);
  STAGE(1, 1);
  asm volatile("s_waitcnt vmcnt(8)" ::: "memory");
  __builtin_amdgcn_s_barrier();

#define PH_OPEN()                                        \
    __builtin_amdgcn_s_barrier();                        \
    asm volatile("s_waitcnt lgkmcnt(0)" ::: "memory");   \
    __builtin_amdgcn_sched_barrier(0);                   \
    __builtin_amdgcn_s_setprio(1)
#define PH_CLOSE()                                       \
    __builtin_amdgcn_s_setprio(0);                       \
    __builtin_amdgcn_sched_barrier(0);                   \
    __builtin_amdgcn_s_barrier()
#define LDA(o) (*(const short8*)(sa + (o)))
#define LDB(o) (*(const short8*)(sb + (o)))

#pragma unroll 2
  for (int t = 0; t < NT; ++t) {
    const unsigned short* sa = lds + (t & 1) * 32768;
    const unsigned short* sb = sa + 16384;
    short8 a[4][2], b01[2][2], b23[2][2];

    // ---------- phase 0 : (m 0-63) x (n 0-31) : 12 ds_reads ----------
#pragma unroll
    for (int mi = 0; mi < 4; ++mi) { a[mi][0] = LDA(aoff[mi]); a[mi][1] = LDA(aoff[mi] ^ 32); }
#pragma unroll
    for (int ni = 0; ni < 2; ++ni) { b01[ni][0] = LDB(boff[ni]); b01[ni][1] = LDB(boff[ni] ^ 32); }
    PH_OPEN();
#pragma unroll
    for (int mi = 0; mi < 4; ++mi)
#pragma unroll
      for (int ni = 0; ni < 2; ++ni)
#pragma unroll
        for (int s = 0; s < 2; ++s)
          acc[mi][ni] = __builtin_amdgcn_mfma_f32_16x16x32_bf16(
              a[mi][s], b01[ni][s], acc[mi][ni], 0, 0, 0);
    PH_CLOSE();

    // ---------- phase 1 : (m 0-63) x (n 32-63) : 4 ds_reads ----------
#pragma unroll
    for (int ni = 0; ni < 2; ++ni) { b23[ni][0] = LDB(boff[ni + 2]); b23[ni][1] = LDB(boff[ni + 2] ^ 32); }
    PH_OPEN();
#pragma unroll
    for (int mi = 0; mi < 4; ++mi)
#pragma unroll
      for (int ni = 0; ni < 2; ++ni)
#pragma unroll
        for (int s = 0; s < 2; ++s)
          acc[mi][ni + 2] = __builtin_amdgcn_mfma_f32_16x16x32_bf16(
              a[mi][s], b23[ni][s], acc[mi][ni + 2], 0, 0, 0);
    PH_CLOSE();

    // ---------- phase 2 : (m 64-127) x (n 0-31) : 8 ds_reads ----------
#pragma unroll
    for (int mi = 0; mi < 4; ++mi) { a[mi][0] = LDA(aoff[mi + 4]); a[mi][1] = LDA(aoff[mi + 4] ^ 32); }
    PH_OPEN();
#pragma unroll
    for (int mi = 0; mi < 4; ++mi)
#pragma unroll
      for (int ni = 0; ni < 2; ++ni)
#pragma unroll
        for (int s = 0; s < 2; ++s)
          acc[mi + 4][ni] = __builtin_amdgcn_mfma_f32_16x16x32_bf16(
              a[mi][s], b01[ni][s], acc[mi + 4][ni], 0, 0, 0);
    PH_CLOSE();

    // ---- phase 3 : (m 64-127) x (n 32-63) + stage tile t+2 ----
    // Staging into buf (t&1) is legal here: all ds_reads of this buf completed
    // before phase 2's closing barrier. Round-2 change: the counted vmcnt(8)
    // moved AFTER the MFMAs (one extra phase ~155cyc of cover for t+1's loads)
    // and phase 3's opening barrier dropped (MFMA-only phase, no sync duty).
    if (t + 2 < NT) STAGE(t & 1, t + 2);
    __builtin_amdgcn_sched_barrier(0);
    __builtin_amdgcn_s_setprio(1);
#pragma unroll
    for (int mi = 0; mi < 4; ++mi)
#pragma unroll
      for (int ni = 0; ni < 2; ++ni)
#pragma unroll
        for (int s = 0; s < 2; ++s)
          acc[mi + 4][ni + 2] = __builtin_amdgcn_mfma_f32_16x16x32_bf16(
              a[mi][s], b23[ni][s], acc[mi + 4][ni + 2], 0, 0, 0);
    __builtin_amdgcn_s_setprio(0);
    __builtin_amdgcn_sched_barrier(0);
    if (t + 2 < NT)
      asm volatile("s_waitcnt vmcnt(8)" ::: "memory");  // t+1's 8 landed; t+2's stay in flight
    else
      asm volatile("s_waitcnt vmcnt(0)" ::: "memory");  // tail: drain
    __builtin_amdgcn_s_barrier();
  }

  // ---------------- epilogue: C = acc + bias ----------------
#pragma unroll
  for (int ni = 0; ni < 4; ++ni) {
    const int gcol = bn0 + wn * 64 + ni * 16 + col16;
#pragma unroll
    for (int mi = 0; mi < 8; ++mi) {
      const int grow = bm0 + wm * 128 + mi * 16 + row4;
#pragma unroll
      for (int r = 0; r < 4; ++r)
        C[(size_t)(grow + r) * N_DIM + gcol] = acc[mi][ni][r] + bv[ni];
    }
  }
}

extern "C" void kernel_launch(void* const* d_in, const int* in_sizes, int n_in,
                              void* d_out, int out_size, void* d_ws, size_t ws_size,
                              hipStream_t stream) {
  const float* x = (const float*)d_in[0];
  const float* W = (const float*)d_in[1];
  const float* b = (const float*)d_in[2];
  float* out = (float*)d_out;

  unsigned short* xb = (unsigned short*)d_ws;
  unsigned short* Wb = xb + (size_t)M_DIM * K_DIM;

  const long ntot = (long)M_DIM * K_DIM + (long)N_DIM * K_DIM;
  cast_both_x8<<<(int)(ntot / (256 * 8)), 256, 0, stream>>>(x, W, xb, Wb);

  gemm_8ph<<<256, 512, 0, stream>>>(xb, Wb, b, out);
}